// Round 7
// baseline (242.692 us; speedup 1.0000x reference)
//
#include <hip/hip_runtime.h>

typedef __attribute__((ext_vector_type(8))) short short8;
typedef __attribute__((ext_vector_type(4))) float floatx4;
typedef __attribute__((ext_vector_type(4))) unsigned short ushort4v;

__device__ __forceinline__ unsigned short f2bf(float f) {
  unsigned int u = __float_as_uint(f);
  u += 0x7FFFu + ((u >> 16) & 1u);           // round-to-nearest-even
  return (unsigned short)(u >> 16);
}

__device__ __forceinline__ unsigned int cvt_pk_bf16(float lo, float hi) {
  unsigned int r;
  asm("v_cvt_pk_bf16_f32 %0, %1, %2" : "=v"(r) : "v"(lo), "v"(hi));
  return r;
}

__device__ __forceinline__ void async_copy16(const void* g, void* l) {
  __builtin_amdgcn_global_load_lds(
      (const __attribute__((address_space(1))) unsigned int*)g,
      (__attribute__((address_space(3))) unsigned int*)l, 16, 0, 0);
}

__device__ __forceinline__ float fexp2(float x) {
#if __has_builtin(__builtin_amdgcn_exp2f)
  return __builtin_amdgcn_exp2f(x);
#else
  return exp2f(x);
#endif
}

// ---------------------------------------------------------------- convert
__global__ __launch_bounds__(256) void cvt_f32_bf16(const float* __restrict__ in,
                                                    unsigned short* __restrict__ out,
                                                    int n4) {
  int i = blockIdx.x * blockDim.x + threadIdx.x;
  if (i >= n4) return;
  float4 v = reinterpret_cast<const float4*>(in)[i];
  ushort4v o;
  o[0] = f2bf(v.x); o[1] = f2bf(v.y); o[2] = f2bf(v.z); o[3] = f2bf(v.w);
  reinterpret_cast<ushort4v*>(out)[i] = o;
}

// ---------------------------------------------------------------- GEMM NT 256x256
// C(M,N) = A(M,K) * B(N,K)^T + bias.  MODE 0: fp32 C out. MODE 1: QKV scatter.
// Phase-split schedule (T3/T4): BM=BN=256, BK=64, 8 waves (2Mx4N), per-wave
// 128x64 output (MFMA:ds_read = 2.67 -- fixes R6's LDS-read-bound 1.33).
// 4 phases per K-tile, each: {stage one 128-row half of tile t+1 || ds_read
// one register subtile || 16-MFMA quadrant}. vmcnt(2) ONCE per K-tile (counted,
// never 0 in steady state). 128KB dbuf LDS, 1 block/CU.
// Race ledger: buffer p^1 half staged at phase q was last READ in tile t-1's
// phases (A-h0:ph1/3 by wr0, A-h1:ph1/3 by wr1, B-h0:ph1/2 by wc01, B-h1 by
// wc23) -- each separated from its stage-issue by >=1 intervening barrier.
// Tile t's writes (issued t-1) are landed before t's reads via vmcnt+barrier.
template <int MODE>
__global__ __launch_bounds__(512) void gemm256(const unsigned short* __restrict__ A,
                                               const unsigned short* __restrict__ B,
                                               const float* __restrict__ bias,
                                               void* __restrict__ C,
                                               int M, int N, int K) {
  __shared__ __align__(16) unsigned short lA[2][256 * 64];
  __shared__ __align__(16) unsigned short lB[2][256 * 64];
  const int tid = threadIdx.x;                 // 0..511
  const int lane = tid & 63, wave = tid >> 6;  // 8 waves
  const int lr = lane & 15, lh = lane >> 4;
  const int m0 = blockIdx.y * 256, n0 = blockIdx.x * 256;
  const int wr = wave >> 2, wc = wave & 3;     // 2(M) x 4(N)
  floatx4 acc[8][4] = {};                      // 128 VGPR

  // stage one 128-row half: 2 x global_load_lds(16B). Source chunk
  // XOR-swizzled by local row&7, LDS linear (rule #21 pairing with reads).
  auto stageHalf = [&](const unsigned short* __restrict__ S, int srow0,
                       unsigned short* lds, int k0) {
#pragma unroll
    for (int c0 = 0; c0 < 1024; c0 += 512) {
      int L = c0 + tid;
      int r = L >> 3;
      int c = (L & 7) ^ (r & 7);
      async_copy16(S + (size_t)(srow0 + r) * K + k0 + c * 8,
                   lds + (size_t)(c0 + wave * 64) * 8);
    }
  };

  // prologue: fully stage K-tile 0
  stageHalf(A, m0,       &lA[0][0],        0);
  stageHalf(A, m0 + 128, &lA[0][128 * 64], 0);
  stageHalf(B, n0,       &lB[0][0],        0);
  stageHalf(B, n0 + 128, &lB[0][128 * 64], 0);

  const int nk = K >> 6;
  short8 af[8], bf0[4], bf1[4];

  for (int t = 0; t < nk; ++t) {
    const int p = t & 1;
    const int k0n = (t + 1) << 6;
    const bool more = (t + 1 < nk);

    // ---- phase 1: stage A-h0(t+1); counted vmcnt; barrier; read A-mh0 + B-nh0; quad(0,0)
    if (more) {
      stageHalf(A, m0, &lA[p ^ 1][0], k0n);
      asm volatile("s_waitcnt vmcnt(2)" ::: "memory");   // tile t's 8 loads done; 2 stay in flight
    } else {
      asm volatile("s_waitcnt vmcnt(0)" ::: "memory");
    }
    __builtin_amdgcn_s_barrier();
    asm volatile("" ::: "memory");
#pragma unroll
    for (int fr = 0; fr < 4; ++fr)
#pragma unroll
      for (int ks = 0; ks < 2; ++ks)
        af[fr * 2 + ks] = *(const short8*)&lA[p][(wr * 128 + fr * 16 + lr) * 64 + (((ks * 4 + lh) ^ (lr & 7)) * 8)];
#pragma unroll
    for (int fc = 0; fc < 2; ++fc)
#pragma unroll
      for (int ks = 0; ks < 2; ++ks)
        bf0[fc * 2 + ks] = *(const short8*)&lB[p][(wc * 64 + fc * 16 + lr) * 64 + (((ks * 4 + lh) ^ (lr & 7)) * 8)];
    __builtin_amdgcn_s_setprio(1);
#pragma unroll
    for (int fr = 0; fr < 4; ++fr)
#pragma unroll
      for (int fc = 0; fc < 2; ++fc)
#pragma unroll
        for (int ks = 0; ks < 2; ++ks)
          acc[fr][fc] = __builtin_amdgcn_mfma_f32_16x16x32_bf16(af[fr * 2 + ks], bf0[fc * 2 + ks], acc[fr][fc], 0, 0, 0);
    __builtin_amdgcn_s_setprio(0);

    // ---- phase 2: stage A-h1(t+1); barrier; read B-nh1; quad(0,1)
    if (more) stageHalf(A, m0 + 128, &lA[p ^ 1][128 * 64], k0n);
    __builtin_amdgcn_s_barrier();
    asm volatile("" ::: "memory");
#pragma unroll
    for (int fc = 0; fc < 2; ++fc)
#pragma unroll
      for (int ks = 0; ks < 2; ++ks)
        bf1[fc * 2 + ks] = *(const short8*)&lB[p][(wc * 64 + 32 + fc * 16 + lr) * 64 + (((ks * 4 + lh) ^ (lr & 7)) * 8)];
    __builtin_amdgcn_s_setprio(1);
#pragma unroll
    for (int fr = 0; fr < 4; ++fr)
#pragma unroll
      for (int fc = 0; fc < 2; ++fc)
#pragma unroll
        for (int ks = 0; ks < 2; ++ks)
          acc[fr][2 + fc] = __builtin_amdgcn_mfma_f32_16x16x32_bf16(af[fr * 2 + ks], bf1[fc * 2 + ks], acc[fr][2 + fc], 0, 0, 0);
    __builtin_amdgcn_s_setprio(0);

    // ---- phase 3: stage B-h0(t+1); barrier; read A-mh1 (reuse af regs); quad(1,0)
    if (more) stageHalf(B, n0, &lB[p ^ 1][0], k0n);
    __builtin_amdgcn_s_barrier();
    asm volatile("" ::: "memory");
#pragma unroll
    for (int fr = 0; fr < 4; ++fr)
#pragma unroll
      for (int ks = 0; ks < 2; ++ks)
        af[fr * 2 + ks] = *(const short8*)&lA[p][(wr * 128 + 64 + fr * 16 + lr) * 64 + (((ks * 4 + lh) ^ (lr & 7)) * 8)];
    __builtin_amdgcn_s_setprio(1);
#pragma unroll
    for (int fr = 0; fr < 4; ++fr)
#pragma unroll
      for (int fc = 0; fc < 2; ++fc)
#pragma unroll
        for (int ks = 0; ks < 2; ++ks)
          acc[4 + fr][fc] = __builtin_amdgcn_mfma_f32_16x16x32_bf16(af[fr * 2 + ks], bf0[fc * 2 + ks], acc[4 + fr][fc], 0, 0, 0);
    __builtin_amdgcn_s_setprio(0);

    // ---- phase 4: stage B-h1(t+1); barrier; quad(1,1) (no ds_read this phase)
    if (more) stageHalf(B, n0 + 128, &lB[p ^ 1][128 * 64], k0n);
    __builtin_amdgcn_s_barrier();
    asm volatile("" ::: "memory");
    __builtin_amdgcn_s_setprio(1);
#pragma unroll
    for (int fr = 0; fr < 4; ++fr)
#pragma unroll
      for (int fc = 0; fc < 2; ++fc)
#pragma unroll
        for (int ks = 0; ks < 2; ++ks)
          acc[4 + fr][2 + fc] = __builtin_amdgcn_mfma_f32_16x16x32_bf16(af[fr * 2 + ks], bf1[fc * 2 + ks], acc[4 + fr][2 + fc], 0, 0, 0);
    __builtin_amdgcn_s_setprio(0);
  }

#pragma unroll
  for (int mf = 0; mf < 8; ++mf)
#pragma unroll
    for (int nf = 0; nf < 4; ++nf)
#pragma unroll
      for (int r = 0; r < 4; ++r) {
        int row = m0 + wr * 128 + (mf >> 2) * 64 + (mf & 3) * 16 + lh * 4 + r;
        int col = n0 + wc * 64 + (nf >> 1) * 32 + (nf & 1) * 16 + lr;
        float v = acc[mf][nf][r] + bias[col];
        if (MODE == 0) {
          ((float*)C)[(size_t)row * N + col] = v;
        } else {
          // row = s*4+b ; col = part*1024 + h*64 + d ; head g = b*16+h
          int part = col >> 10, wi = col & 1023;
          int h = wi >> 6, dd = wi & 63;
          int s = row >> 2, b = row & 3;
          int gg = b * 16 + h;
          size_t base = (size_t)part * (64u * 2048u * 64u);
          if (part == 0) {
            // fold 1/sqrt(d_k) * log2(e) into Q (softmax runs in log2 domain)
            v *= 0.18033688011112042f;
            ((unsigned short*)C)[base + ((size_t)gg * 2048 + s) * 64 + dd] = f2bf(v);
          } else if (part == 1) {
            ((unsigned short*)C)[base + ((size_t)gg * 2048 + s) * 64 + dd] = f2bf(v);
          } else {
            // V stored TRANSPOSED per head: Vt[g][d][s]
            ((unsigned short*)C)[base + ((size_t)gg * 64 + dd) * 2048 + s] = f2bf(v);
          }
        }
      }
}

// ---------------------------------------------------------------- attention
// 1024 blocks (XCD-swizzled: one XCD owns 8 heads x 16 q-tiles; qt remapped so
// every CU's 4 blocks total exactly 68 KV tiles under causal).
// 4 waves x 32 q-rows, KV tile = 64, double-buffered pipelined staging.
// Swapped QK^T: S^T = mfma(K, Q) so each lane owns 16 S-values of ONE q-row.
__global__ __launch_bounds__(256, 3) void attn_fwd(const unsigned short* __restrict__ Qb,
                                                   const unsigned short* __restrict__ Kb,
                                                   const unsigned short* __restrict__ Vt,
                                                   unsigned short* __restrict__ Att,
                                                   const int* __restrict__ causal_p) {
  __shared__ __align__(16) unsigned short lK[2][64 * 64];
  __shared__ __align__(16) unsigned short lV[2][64 * 64];   // Vt tile: rows=d, cols=kv
  __shared__ __align__(16) unsigned short lP[4][32 * 64];   // per-wave P, XOR-swizzled
  const int tid = threadIdx.x;
  const int lane = tid & 63, w = tid >> 6;
  const int lr = lane & 15, lh = lane >> 4;
  const int bid = blockIdx.x;
  const int g = (bid & 7) + 8 * (bid >> 7);
  int qt = (bid >> 3) & 15;
  qt = (qt & 12) | ((qt ^ (qt >> 2)) & 3);    // per-CU causal load balance (bijective)
  const int q0 = qt * 128;
  const int causal = causal_p[0];
  const size_t headOff = (size_t)g * 2048 * 64;
  const size_t vtHead = (size_t)g * 64 * 2048;
  const int q0w = q0 + w * 32;

  short8 qf[2][2];
#pragma unroll
  for (int qb = 0; qb < 2; ++qb)
#pragma unroll
    for (int kf = 0; kf < 2; ++kf)
      qf[qb][kf] = *(const short8*)&Qb[headOff + (size_t)(q0w + qb * 16 + lr) * 64 + kf * 32 + lh * 8];

  floatx4 oacc[2][4] = {};
  float mrow[2] = {-1e30f, -1e30f}, lrow[2] = {0.f, 0.f};

  const int nt = causal ? (q0 + 128) / 64 : 2048 / 64;
  const int qmax_w = q0w + 31;

  // staging: source-side XOR swizzle (chunk c ^= row&7), linear LDS dest.
  auto stageK = [&](int buf, int kv0) {
#pragma unroll
    for (int c0 = 0; c0 < 512; c0 += 256) {
      int L = c0 + tid;
      int kvr = L >> 3;
      int c = (tid & 7) ^ (kvr & 7);
      async_copy16(Kb + headOff + (size_t)(kv0 + kvr) * 64 + c * 8,
                   &lK[buf][(size_t)(c0 + w * 64) * 8]);
    }
  };
  auto stageV = [&](int buf, int kv0) {
#pragma unroll
    for (int c0 = 0; c0 < 512; c0 += 256) {
      int L = c0 + tid;
      int dr = L >> 3;
      int c = (tid & 7) ^ (dr & 7);
      async_copy16(Vt + vtHead + (size_t)dr * 2048 + kv0 + c * 8,
                   &lV[buf][(size_t)(c0 + w * 64) * 8]);
    }
  };

  stageK(0, 0);
  stageV(0, 0);
  int cur = 0;

  for (int t = 0; t < nt; ++t) {
    const int kv0 = t * 64;
    if (t + 1 < nt) {
      stageK(cur ^ 1, kv0 + 64);
      stageV(cur ^ 1, kv0 + 64);
      asm volatile("s_waitcnt vmcnt(4)" ::: "memory");  // tile t's 4 loads done
    } else {
      asm volatile("s_waitcnt vmcnt(0)" ::: "memory");
    }
    __builtin_amdgcn_s_barrier();
    asm volatile("" ::: "memory");

    if (!causal || kv0 <= qmax_w) {
      // ---- S^T = K * Q^T : sacc[qb][nf][r] = S[q = q0w+qb*16+lr][kv = kv0+nf*16+lh*4+r]
      floatx4 sacc[2][4] = {};
      __builtin_amdgcn_s_setprio(1);
#pragma unroll
      for (int kk = 0; kk < 2; ++kk) {
        short8 kfr[4];
#pragma unroll
        for (int nf = 0; nf < 4; ++nf)
          kfr[nf] = *(const short8*)&lK[cur][(nf * 16 + lr) * 64 + (((kk * 4 + lh) ^ (lr & 7)) * 8)];
#pragma unroll
        for (int qb = 0; qb < 2; ++qb)
#pragma unroll
          for (int nf = 0; nf < 4; ++nf)
            sacc[qb][nf] = __builtin_amdgcn_mfma_f32_16x16x32_bf16(kfr[nf], qf[qb][kk], sacc[qb][nf], 0, 0, 0);
      }
      __builtin_amdgcn_s_setprio(0);

      if (causal && kv0 + 63 > q0w) {
#pragma unroll
        for (int qb = 0; qb < 2; ++qb) {
          int q = q0w + qb * 16 + lr;
#pragma unroll
          for (int nf = 0; nf < 4; ++nf)
#pragma unroll
            for (int r = 0; r < 4; ++r) {
              int kv = kv0 + nf * 16 + lh * 4 + r;
              if (kv > q) sacc[qb][nf][r] = -1e30f;
            }
        }
      }

      // ---- online softmax: stats lane-local per q (lanes sharing lr share q)
      float alpha[2];
#pragma unroll
      for (int qb = 0; qb < 2; ++qb) {
        float rm = -1e30f;
#pragma unroll
        for (int nf = 0; nf < 4; ++nf)
          rm = fmaxf(rm, fmaxf(fmaxf(sacc[qb][nf][0], sacc[qb][nf][1]),
                               fmaxf(sacc[qb][nf][2], sacc[qb][nf][3])));
        rm = fmaxf(rm, __shfl_xor(rm, 16, 64));
        rm = fmaxf(rm, __shfl_xor(rm, 32, 64));
        float mn = fmaxf(mrow[qb], rm);
        alpha[qb] = fexp2(mrow[qb] - mn);
        mrow[qb] = mn;
        float rs = 0.f;
#pragma unroll
        for (int nf = 0; nf < 4; ++nf)
#pragma unroll
          for (int r = 0; r < 4; ++r) {
            float p = fexp2(sacc[qb][nf][r] - mn);
            sacc[qb][nf][r] = p;
            rs += p;
          }
        rs += __shfl_xor(rs, 16, 64);
        rs += __shfl_xor(rs, 32, 64);
        lrow[qb] = lrow[qb] * alpha[qb] + rs;
      }

      // ---- P -> LDS: pack 4 contiguous kv per lane, XOR-swizzled, ds_write_b64
#pragma unroll
      for (int qb = 0; qb < 2; ++qb)
#pragma unroll
        for (int nf = 0; nf < 4; ++nf) {
          uint2 pk;
          pk.x = cvt_pk_bf16(sacc[qb][nf][0], sacc[qb][nf][1]);
          pk.y = cvt_pk_bf16(sacc[qb][nf][2], sacc[qb][nf][3]);
          int c = (2 * nf + (lh >> 1)) ^ (lr & 7);
          *(uint2*)&lP[w][(qb * 16 + lr) * 64 + c * 8 + (lh & 1) * 4] = pk;
        }

      // ---- rescale O with alpha transposed to the accumulator row domain
#pragma unroll
      for (int qb = 0; qb < 2; ++qb) {
        float at[4];
#pragma unroll
        for (int r = 0; r < 4; ++r)
          at[r] = __shfl(alpha[qb], lh * 4 + r, 64);
#pragma unroll
        for (int nd = 0; nd < 4; ++nd)
#pragma unroll
          for (int r = 0; r < 4; ++r)
            oacc[qb][nd][r] *= at[r];
      }

      // ---- PV: O += P * Vt^T
      __builtin_amdgcn_s_setprio(1);
#pragma unroll
      for (int kk = 0; kk < 2; ++kk) {
        short8 pf[2], vf[4];
#pragma unroll
        for (int qb = 0; qb < 2; ++qb)
          pf[qb] = *(const short8*)&lP[w][(qb * 16 + lr) * 64 + (((kk * 4 + lh) ^ (lr & 7)) * 8)];
#pragma unroll
        for (int nd = 0; nd < 4; ++nd)
          vf[nd] = *(const short8*)&lV[cur][(nd * 16 + lr) * 64 + (((kk * 4 + lh) ^ (lr & 7)) * 8)];
#pragma unroll
        for (int qb = 0; qb < 2; ++qb)
#pragma unroll
          for (int nd = 0; nd < 4; ++nd)
            oacc[qb][nd] = __builtin_amdgcn_mfma_f32_16x16x32_bf16(pf[qb], vf[nd], oacc[qb][nd], 0, 0, 0);
      }
      __builtin_amdgcn_s_setprio(0);
    }
    asm volatile("" ::: "memory");
    __builtin_amdgcn_s_barrier();   // everyone done reading buf[cur] before overwrite
    cur ^= 1;
  }

  const int bb = g >> 4, hh = g & 15;
#pragma unroll
  for (int qb = 0; qb < 2; ++qb) {
    float invl = 1.f / lrow[qb];
    float it[4];
#pragma unroll
    for (int r = 0; r < 4; ++r)
      it[r] = __shfl(invl, lh * 4 + r, 64);
#pragma unroll
    for (int r = 0; r < 4; ++r) {
      int s = q0w + qb * 16 + lh * 4 + r;
#pragma unroll
      for (int nd = 0; nd < 4; ++nd) {
        int dd = nd * 16 + lr;
        Att[((size_t)s * 4 + bb) * 1024 + hh * 64 + dd] = f2bf(oacc[qb][nd][r] * it[r]);
      }
    }
  }
}

// ---------------------------------------------------------------- launcher
extern "C" void kernel_launch(void* const* d_in, const int* in_sizes, int n_in,
                              void* d_out, int out_size, void* d_ws, size_t ws_size,
                              hipStream_t stream) {
  const float* x     = (const float*)d_in[0];
  const float* w_qkv = (const float*)d_in[1];
  const float* b_qkv = (const float*)d_in[2];
  const float* w_out = (const float*)d_in[3];
  const float* b_out = (const float*)d_in[4];
  const int*   causal = (const int*)d_in[5];
  float* out = (float*)d_out;

  char* ws = (char*)d_ws;
  size_t off = 0;
  auto alloc = [&](size_t bytes) { char* p = ws + off; off += (bytes + 255) & ~(size_t)255; return p; };
  unsigned short* Xbf  = (unsigned short*)alloc((size_t)8192 * 1024 * 2);
  unsigned short* Wqkv = (unsigned short*)alloc((size_t)3072 * 1024 * 2);
  unsigned short* Wout = (unsigned short*)alloc((size_t)1024 * 1024 * 2);
  unsigned short* QKV  = (unsigned short*)alloc((size_t)3 * 64 * 2048 * 64 * 2);
  unsigned short* Att  = (unsigned short*)alloc((size_t)8192 * 1024 * 2);
  (void)ws_size; (void)in_sizes; (void)n_in; (void)out_size;

  cvt_f32_bf16<<<8192, 256, 0, stream>>>(x, Xbf, 8192 * 1024 / 4);
  cvt_f32_bf16<<<3072, 256, 0, stream>>>(w_qkv, Wqkv, 3072 * 1024 / 4);
  cvt_f32_bf16<<<1024, 256, 0, stream>>>(w_out, Wout, 1024 * 1024 / 4);

  gemm256<1><<<dim3(12, 32), 512, 0, stream>>>(Xbf, Wqkv, b_qkv, (void*)QKV, 8192, 3072, 1024);

  const unsigned short* Qh = QKV;
  const unsigned short* Kh = QKV + (size_t)64 * 2048 * 64;
  const unsigned short* Vh = QKV + (size_t)2 * 64 * 2048 * 64;
  attn_fwd<<<1024, 256, 0, stream>>>(Qh, Kh, Vh, Att, causal);

  gemm256<0><<<dim3(4, 32), 512, 0, stream>>>(Att, Wout, b_out, (void*)out, 8192, 1024, 1024);
}

// Round 8
// 196.615 us; speedup vs baseline: 1.2344x; 1.2344x over previous
//
#include <hip/hip_runtime.h>

typedef __attribute__((ext_vector_type(8))) short short8;
typedef __attribute__((ext_vector_type(4))) float floatx4;
typedef __attribute__((ext_vector_type(4))) unsigned short ushort4v;

__device__ __forceinline__ unsigned short f2bf(float f) {
  unsigned int u = __float_as_uint(f);
  u += 0x7FFFu + ((u >> 16) & 1u);           // round-to-nearest-even
  return (unsigned short)(u >> 16);
}

__device__ __forceinline__ unsigned int cvt_pk_bf16(float lo, float hi) {
  unsigned int r;
  asm("v_cvt_pk_bf16_f32 %0, %1, %2" : "=v"(r) : "v"(lo), "v"(hi));
  return r;
}

__device__ __forceinline__ void async_copy16(const void* g, void* l) {
  __builtin_amdgcn_global_load_lds(
      (const __attribute__((address_space(1))) unsigned int*)g,
      (__attribute__((address_space(3))) unsigned int*)l, 16, 0, 0);
}

__device__ __forceinline__ float fexp2(float x) {
#if __has_builtin(__builtin_amdgcn_exp2f)
  return __builtin_amdgcn_exp2f(x);
#else
  return exp2f(x);
#endif
}

// ---------------------------------------------------------------- convert
__global__ __launch_bounds__(256) void cvt_f32_bf16(const float* __restrict__ in,
                                                    unsigned short* __restrict__ out,
                                                    int n4) {
  int i = blockIdx.x * blockDim.x + threadIdx.x;
  if (i >= n4) return;
  float4 v = reinterpret_cast<const float4*>(in)[i];
  ushort4v o;
  o[0] = f2bf(v.x); o[1] = f2bf(v.y); o[2] = f2bf(v.z); o[3] = f2bf(v.w);
  reinterpret_cast<ushort4v*>(out)[i] = o;
}

// ---------------------------------------------------------------- GEMM NT
// C(M,N) = A(M,K) * B(N,K)^T + bias.  MODE 0: fp32 C out. MODE 1: QKV scatter.
// m97 geometry: 128x128 tile, 4 waves (2x2), wave-tile 64x64 (32 MFMA : 16
// ds_read_b128 = 2.0), single 32KB LDS buffer, classic 2-barrier K-loop —
// block residency (4/CU via launch_bounds(256,4), VGPR cap 128 >= ~88 used)
// does the latency hiding (m114). Source-side XOR swizzle: conflicts = 0.
// XCD-chunked grid swizzle: 1D grid, xcd = bid&7 owns a contiguous slice of
// m-tiles (A-slice ~2.1MB resident per XCD L2), B streamed once per XCD.
template <int MODE, int NX>
__global__ __launch_bounds__(256, 4) void gemm_nt(const unsigned short* __restrict__ A,
                                                  const unsigned short* __restrict__ B,
                                                  const float* __restrict__ bias,
                                                  void* __restrict__ C,
                                                  int M, int N, int K) {
  __shared__ __align__(16) unsigned short lA[128 * 64];
  __shared__ __align__(16) unsigned short lB[128 * 64];
  const int tid = threadIdx.x;
  const int lane = tid & 63, wave = tid >> 6;
  const int lr = lane & 15, lh = lane >> 4;
  // XCD-chunked bijective decode (gridDim.x divisible by 8)
  const int chunk = gridDim.x >> 3;
  const int g2 = (blockIdx.x & 7) * chunk + (blockIdx.x >> 3);
  const int m0 = (g2 / NX) * 128, n0 = (g2 % NX) * 128;
  const int wm = (wave >> 1) * 64, wn = (wave & 1) * 64;
  floatx4 acc[4][4] = {};

  for (int k0 = 0; k0 < K; k0 += 64) {
    __syncthreads();   // all waves done reading previous tile
    // source-side XOR swizzle (chunk ^= row&7), linear LDS dest
#pragma unroll
    for (int c0 = 0; c0 < 1024; c0 += 256) {
      int L = c0 + tid;
      int r = L >> 3;
      int c = (L & 7) ^ (r & 7);
      async_copy16(A + (size_t)(m0 + r) * K + k0 + c * 8, &lA[(size_t)(c0 + wave * 64) * 8]);
      async_copy16(B + (size_t)(n0 + r) * K + k0 + c * 8, &lB[(size_t)(c0 + wave * 64) * 8]);
    }
    __syncthreads();   // tile resident
#pragma unroll
    for (int kk = 0; kk < 2; ++kk) {
      short8 af[4], bfr[4];
#pragma unroll
      for (int mf = 0; mf < 4; ++mf)
        af[mf] = *(const short8*)&lA[(wm + mf * 16 + lr) * 64 + (((kk * 4 + lh) ^ (lr & 7)) * 8)];
#pragma unroll
      for (int nf = 0; nf < 4; ++nf)
        bfr[nf] = *(const short8*)&lB[(wn + nf * 16 + lr) * 64 + (((kk * 4 + lh) ^ (lr & 7)) * 8)];
#pragma unroll
      for (int mf = 0; mf < 4; ++mf)
#pragma unroll
        for (int nf = 0; nf < 4; ++nf)
          acc[mf][nf] = __builtin_amdgcn_mfma_f32_16x16x32_bf16(af[mf], bfr[nf], acc[mf][nf], 0, 0, 0);
    }
  }

#pragma unroll
  for (int mf = 0; mf < 4; ++mf)
#pragma unroll
    for (int nf = 0; nf < 4; ++nf)
#pragma unroll
      for (int r = 0; r < 4; ++r) {
        int row = m0 + wm + mf * 16 + lh * 4 + r;   // C row (m)
        int col = n0 + wn + nf * 16 + lr;           // C col (n)
        float v = acc[mf][nf][r] + bias[col];
        if (MODE == 0) {
          ((float*)C)[(size_t)row * N + col] = v;
        } else {
          // row = s*4+b ; col = part*1024 + h*64 + d ; head g = b*16+h
          int part = col >> 10, wi = col & 1023;
          int h = wi >> 6, dd = wi & 63;
          int s = row >> 2, b = row & 3;
          int gg = b * 16 + h;
          size_t base = (size_t)part * (64u * 2048u * 64u);
          if (part == 0) {
            // fold 1/sqrt(d_k) * log2(e) into Q (softmax runs in log2 domain)
            v *= 0.18033688011112042f;
            ((unsigned short*)C)[base + ((size_t)gg * 2048 + s) * 64 + dd] = f2bf(v);
          } else if (part == 1) {
            ((unsigned short*)C)[base + ((size_t)gg * 2048 + s) * 64 + dd] = f2bf(v);
          } else {
            // V stored TRANSPOSED per head: Vt[g][d][s]
            ((unsigned short*)C)[base + ((size_t)gg * 64 + dd) * 2048 + s] = f2bf(v);
          }
        }
      }
}

// ---------------------------------------------------------------- attention
// 1024 blocks (XCD-swizzled: one XCD owns 8 heads x 16 q-tiles; qt remapped so
// every CU's 4 blocks total exactly 68 KV tiles under causal).
// 4 waves x 32 q-rows, KV tile = 64, double-buffered pipelined staging.
// Swapped QK^T: S^T = mfma(K, Q) so each lane owns 16 S-values of ONE q-row.
__global__ __launch_bounds__(256, 3) void attn_fwd(const unsigned short* __restrict__ Qb,
                                                   const unsigned short* __restrict__ Kb,
                                                   const unsigned short* __restrict__ Vt,
                                                   unsigned short* __restrict__ Att,
                                                   const int* __restrict__ causal_p) {
  __shared__ __align__(16) unsigned short lK[2][64 * 64];
  __shared__ __align__(16) unsigned short lV[2][64 * 64];   // Vt tile: rows=d, cols=kv
  __shared__ __align__(16) unsigned short lP[4][32 * 64];   // per-wave P, XOR-swizzled
  const int tid = threadIdx.x;
  const int lane = tid & 63, w = tid >> 6;
  const int lr = lane & 15, lh = lane >> 4;
  const int bid = blockIdx.x;
  const int g = (bid & 7) + 8 * (bid >> 7);
  int qt = (bid >> 3) & 15;
  qt = (qt & 12) | ((qt ^ (qt >> 2)) & 3);    // per-CU causal load balance (bijective)
  const int q0 = qt * 128;
  const int causal = causal_p[0];
  const size_t headOff = (size_t)g * 2048 * 64;
  const size_t vtHead = (size_t)g * 64 * 2048;
  const int q0w = q0 + w * 32;

  short8 qf[2][2];
#pragma unroll
  for (int qb = 0; qb < 2; ++qb)
#pragma unroll
    for (int kf = 0; kf < 2; ++kf)
      qf[qb][kf] = *(const short8*)&Qb[headOff + (size_t)(q0w + qb * 16 + lr) * 64 + kf * 32 + lh * 8];

  floatx4 oacc[2][4] = {};
  float mrow[2] = {-1e30f, -1e30f}, lrow[2] = {0.f, 0.f};

  const int nt = causal ? (q0 + 128) / 64 : 2048 / 64;
  const int qmax_w = q0w + 31;

  // staging: source-side XOR swizzle (chunk c ^= row&7), linear LDS dest.
  auto stageK = [&](int buf, int kv0) {
#pragma unroll
    for (int c0 = 0; c0 < 512; c0 += 256) {
      int L = c0 + tid;
      int kvr = L >> 3;
      int c = (tid & 7) ^ (kvr & 7);
      async_copy16(Kb + headOff + (size_t)(kv0 + kvr) * 64 + c * 8,
                   &lK[buf][(size_t)(c0 + w * 64) * 8]);
    }
  };
  auto stageV = [&](int buf, int kv0) {
#pragma unroll
    for (int c0 = 0; c0 < 512; c0 += 256) {
      int L = c0 + tid;
      int dr = L >> 3;
      int c = (tid & 7) ^ (dr & 7);
      async_copy16(Vt + vtHead + (size_t)dr * 2048 + kv0 + c * 8,
                   &lV[buf][(size_t)(c0 + w * 64) * 8]);
    }
  };

  stageK(0, 0);
  stageV(0, 0);
  int cur = 0;

  for (int t = 0; t < nt; ++t) {
    const int kv0 = t * 64;
    if (t + 1 < nt) {
      stageK(cur ^ 1, kv0 + 64);
      stageV(cur ^ 1, kv0 + 64);
      asm volatile("s_waitcnt vmcnt(4)" ::: "memory");  // tile t's 4 loads done
    } else {
      asm volatile("s_waitcnt vmcnt(0)" ::: "memory");
    }
    __builtin_amdgcn_s_barrier();
    asm volatile("" ::: "memory");

    if (!causal || kv0 <= qmax_w) {
      // ---- S^T = K * Q^T : sacc[qb][nf][r] = S[q = q0w+qb*16+lr][kv = kv0+nf*16+lh*4+r]
      floatx4 sacc[2][4] = {};
      __builtin_amdgcn_s_setprio(1);
#pragma unroll
      for (int kk = 0; kk < 2; ++kk) {
        short8 kfr[4];
#pragma unroll
        for (int nf = 0; nf < 4; ++nf)
          kfr[nf] = *(const short8*)&lK[cur][(nf * 16 + lr) * 64 + (((kk * 4 + lh) ^ (lr & 7)) * 8)];
#pragma unroll
        for (int qb = 0; qb < 2; ++qb)
#pragma unroll
          for (int nf = 0; nf < 4; ++nf)
            sacc[qb][nf] = __builtin_amdgcn_mfma_f32_16x16x32_bf16(kfr[nf], qf[qb][kk], sacc[qb][nf], 0, 0, 0);
      }
      __builtin_amdgcn_s_setprio(0);

      if (causal && kv0 + 63 > q0w) {
#pragma unroll
        for (int qb = 0; qb < 2; ++qb) {
          int q = q0w + qb * 16 + lr;
#pragma unroll
          for (int nf = 0; nf < 4; ++nf)
#pragma unroll
            for (int r = 0; r < 4; ++r) {
              int kv = kv0 + nf * 16 + lh * 4 + r;
              if (kv > q) sacc[qb][nf][r] = -1e30f;
            }
        }
      }

      // ---- online softmax: stats lane-local per q (lanes sharing lr share q)
      float alpha[2];
#pragma unroll
      for (int qb = 0; qb < 2; ++qb) {
        float rm = -1e30f;
#pragma unroll
        for (int nf = 0; nf < 4; ++nf)
          rm = fmaxf(rm, fmaxf(fmaxf(sacc[qb][nf][0], sacc[qb][nf][1]),
                               fmaxf(sacc[qb][nf][2], sacc[qb][nf][3])));
        rm = fmaxf(rm, __shfl_xor(rm, 16, 64));
        rm = fmaxf(rm, __shfl_xor(rm, 32, 64));
        float mn = fmaxf(mrow[qb], rm);
        alpha[qb] = fexp2(mrow[qb] - mn);
        mrow[qb] = mn;
        float rs = 0.f;
#pragma unroll
        for (int nf = 0; nf < 4; ++nf)
#pragma unroll
          for (int r = 0; r < 4; ++r) {
            float p = fexp2(sacc[qb][nf][r] - mn);
            sacc[qb][nf][r] = p;
            rs += p;
          }
        rs += __shfl_xor(rs, 16, 64);
        rs += __shfl_xor(rs, 32, 64);
        lrow[qb] = lrow[qb] * alpha[qb] + rs;
      }

      // ---- P -> LDS: pack 4 contiguous kv per lane, XOR-swizzled, ds_write_b64
#pragma unroll
      for (int qb = 0; qb < 2; ++qb)
#pragma unroll
        for (int nf = 0; nf < 4; ++nf) {
          uint2 pk;
          pk.x = cvt_pk_bf16(sacc[qb][nf][0], sacc[qb][nf][1]);
          pk.y = cvt_pk_bf16(sacc[qb][nf][2], sacc[qb][nf][3]);
          int c = (2 * nf + (lh >> 1)) ^ (lr & 7);
          *(uint2*)&lP[w][(qb * 16 + lr) * 64 + c * 8 + (lh & 1) * 4] = pk;
        }

      // ---- rescale O with alpha transposed to the accumulator row domain
#pragma unroll
      for (int qb = 0; qb < 2; ++qb) {
        float at[4];
#pragma unroll
        for (int r = 0; r < 4; ++r)
          at[r] = __shfl(alpha[qb], lh * 4 + r, 64);
#pragma unroll
        for (int nd = 0; nd < 4; ++nd)
#pragma unroll
          for (int r = 0; r < 4; ++r)
            oacc[qb][nd][r] *= at[r];
      }

      // ---- PV: O += P * Vt^T
      __builtin_amdgcn_s_setprio(1);
#pragma unroll
      for (int kk = 0; kk < 2; ++kk) {
        short8 pf[2], vf[4];
#pragma unroll
        for (int qb = 0; qb < 2; ++qb)
          pf[qb] = *(const short8*)&lP[w][(qb * 16 + lr) * 64 + (((kk * 4 + lh) ^ (lr & 7)) * 8)];
#pragma unroll
        for (int nd = 0; nd < 4; ++nd)
          vf[nd] = *(const short8*)&lV[cur][(nd * 16 + lr) * 64 + (((kk * 4 + lh) ^ (lr & 7)) * 8)];
#pragma unroll
        for (int qb = 0; qb < 2; ++qb)
#pragma unroll
          for (int nd = 0; nd < 4; ++nd)
            oacc[qb][nd] = __builtin_amdgcn_mfma_f32_16x16x32_bf16(pf[qb], vf[nd], oacc[qb][nd], 0, 0, 0);
      }
      __builtin_amdgcn_s_setprio(0);
    }
    asm volatile("" ::: "memory");
    __builtin_amdgcn_s_barrier();   // everyone done reading buf[cur] before overwrite
    cur ^= 1;
  }

  const int bb = g >> 4, hh = g & 15;
#pragma unroll
  for (int qb = 0; qb < 2; ++qb) {
    float invl = 1.f / lrow[qb];
    float it[4];
#pragma unroll
    for (int r = 0; r < 4; ++r)
      it[r] = __shfl(invl, lh * 4 + r, 64);
#pragma unroll
    for (int r = 0; r < 4; ++r) {
      int s = q0w + qb * 16 + lh * 4 + r;
#pragma unroll
      for (int nd = 0; nd < 4; ++nd) {
        int dd = nd * 16 + lr;
        Att[((size_t)s * 4 + bb) * 1024 + hh * 64 + dd] = f2bf(oacc[qb][nd][r] * it[r]);
      }
    }
  }
}

// ---------------------------------------------------------------- launcher
extern "C" void kernel_launch(void* const* d_in, const int* in_sizes, int n_in,
                              void* d_out, int out_size, void* d_ws, size_t ws_size,
                              hipStream_t stream) {
  const float* x     = (const float*)d_in[0];
  const float* w_qkv = (const float*)d_in[1];
  const float* b_qkv = (const float*)d_in[2];
  const float* w_out = (const float*)d_in[3];
  const float* b_out = (const float*)d_in[4];
  const int*   causal = (const int*)d_in[5];
  float* out = (float*)d_out;

  char* ws = (char*)d_ws;
  size_t off = 0;
  auto alloc = [&](size_t bytes) { char* p = ws + off; off += (bytes + 255) & ~(size_t)255; return p; };
  unsigned short* Xbf  = (unsigned short*)alloc((size_t)8192 * 1024 * 2);
  unsigned short* Wqkv = (unsigned short*)alloc((size_t)3072 * 1024 * 2);
  unsigned short* Wout = (unsigned short*)alloc((size_t)1024 * 1024 * 2);
  unsigned short* QKV  = (unsigned short*)alloc((size_t)3 * 64 * 2048 * 64 * 2);
  unsigned short* Att  = (unsigned short*)alloc((size_t)8192 * 1024 * 2);
  (void)ws_size; (void)in_sizes; (void)n_in; (void)out_size;

  cvt_f32_bf16<<<8192, 256, 0, stream>>>(x, Xbf, 8192 * 1024 / 4);
  cvt_f32_bf16<<<3072, 256, 0, stream>>>(w_qkv, Wqkv, 3072 * 1024 / 4);
  cvt_f32_bf16<<<1024, 256, 0, stream>>>(w_out, Wout, 1024 * 1024 / 4);

  // 1D grid, XCD-chunked decode inside; nwg divisible by 8
  gemm_nt<1, 24><<<24 * 64, 256, 0, stream>>>(Xbf, Wqkv, b_qkv, (void*)QKV, 8192, 3072, 1024);

  const unsigned short* Qh = QKV;
  const unsigned short* Kh = QKV + (size_t)64 * 2048 * 64;
  const unsigned short* Vh = QKV + (size_t)2 * 64 * 2048 * 64;
  attn_fwd<<<1024, 256, 0, stream>>>(Qh, Kh, Vh, Att, causal);

  gemm_nt<0, 8><<<8 * 64, 256, 0, stream>>>(Att, Wout, b_out, (void*)out, 8192, 1024, 1024);
}